// Round 14
// baseline (274.978 us; speedup 1.0000x reference)
//
#include <hip/hip_runtime.h>
#include <hip/hip_bf16.h>

// GAT 2-layer, N=50000, E=800000, D=128, H=2, F=128, C=H*F=256.
// Round 14: aggregate VALU diet (now that it IS VALU-bound, 70-73% r13):
//  - alpha_kernel: per-edge unnormalized exp-scores in CSR order (1 pass) +
//    per-node den; kills the 64-lane-redundant exp in the aggregate.
//  - aggregate hot loop: pure alpha-weighted bf16 gather (broadcast alpha).
//  - agg stored as bf16 hi/lo planes (fp32-equiv): gemm A-frags load directly,
//    no in-register f2bf split.
// Pipeline: init -> hist -> scan -> scatter -> elr1 -> alpha -> agg -> gemm1
//           -> alpha -> agg -> gemm2.

#define NEG_SLOPE 0.2f

typedef __attribute__((ext_vector_type(8))) short bf16x8_t;
typedef __attribute__((ext_vector_type(4))) float f32x4_t;

__device__ __forceinline__ unsigned short f2bf(float f) {
  union { float f; unsigned int u; } v; v.f = f;
  unsigned int r = v.u + 0x7FFFu + ((v.u >> 16) & 1u);
  return (unsigned short)(r >> 16);
}
__device__ __forceinline__ float bfbits(unsigned int hi16) {
  union { unsigned int u; float f; } v; v.u = hi16;
  return v.f;
}
__device__ __forceinline__ unsigned int pack_hilo(float a, float b,
                                                  unsigned int* lo) {
  unsigned short ha = f2bf(a), hb = f2bf(b);
  float ra = a - bfbits((unsigned int)ha << 16);
  float rb = b - bfbits((unsigned int)hb << 16);
  *lo = (unsigned int)f2bf(ra) | ((unsigned int)f2bf(rb) << 16);
  return (unsigned int)ha | ((unsigned int)hb << 16);
}

// ---------------- init: wpack + wal/war + x->bf16 + zero counts/tstate -------

__global__ __launch_bounds__(256) void init_kernel(
    const float* __restrict__ Ws, const float* __restrict__ als,
    const float* __restrict__ ars, const float* __restrict__ x,
    unsigned short* __restrict__ Whi, unsigned short* __restrict__ Wlo,
    float* __restrict__ wal, float* __restrict__ war,
    unsigned short* __restrict__ xb16,
    int* __restrict__ counts, unsigned int* __restrict__ tstate, int n)
{
  const int b = blockIdx.x;
  const int t = threadIdx.x;
  const int nxb = (n * 128 + 1023) >> 10;
  if (b < 32) {
    int tg = b * 256 + t;
    int t2 = tg & 4095;
    int lane = t2 & 63;
    int ct3 = (t2 >> 6) & 7;
    int s = (t2 >> 9) & 3;
    int hb = (t2 >> 11) & 1;
    int lay = tg >> 12;
    int col = hb * 128 + ct3 * 16 + (lane & 15);
    int kbase = s * 32 + (lane >> 4) * 8;
    size_t obase = (size_t)lay * 32768 + (size_t)hb * 16384 + (size_t)(t2 & 2047) * 8;
    #pragma unroll
    for (int j = 0; j < 8; ++j) {
      float w = Ws[(size_t)lay * 32768 + (size_t)(kbase + j) * 256 + col];
      unsigned short hb16 = f2bf(w);
      float rem = w - bfbits((unsigned int)hb16 << 16);
      Whi[obase + j] = hb16;
      Wlo[obase + j] = f2bf(rem);
    }
  } else if (b < 36) {
    int tg = (b - 32) * 256 + t;           // 0..1023
    int lr = tg >> 9;
    int rem = tg & 511;
    int lay = rem >> 8, h = (rem >> 7) & 1, k = rem & 127;
    const float* a = (lr ? ars : als) + (size_t)lay * 256 + h * 128;
    const float* wrow = Ws + (size_t)lay * 32768 + (size_t)k * 256 + h * 128;
    float sum = 0.f;
    for (int f = 0; f < 128; ++f) sum = fmaf(wrow[f], a[f], sum);
    (lr ? war : wal)[(size_t)lay * 256 + h * 128 + k] = sum;
  } else if (b < 36 + nxb) {
    int idx = (b - 36) * 1024 + t * 4;
    int nf = n * 128;
    if (idx + 3 < nf) {
      float4 v = *(const float4*)&x[idx];
      ushort4 p;
      p.x = f2bf(v.x); p.y = f2bf(v.y); p.z = f2bf(v.z); p.w = f2bf(v.w);
      *(ushort4*)&xb16[idx] = p;
    } else {
      for (int i = 0; i < 4 && idx + i < nf; ++i) xb16[idx + i] = f2bf(x[idx + i]);
    }
  } else {
    int idx = (b - 36 - nxb) * 256 + t;
    if (idx < n) counts[idx] = 0;
    if (idx < 64) tstate[idx] = 0u;
  }
}

// ---------------- hist ----------------

__global__ void hist_kernel(const int* __restrict__ dst, int* __restrict__ counts, int n_edges) {
  int e = blockIdx.x * blockDim.x + threadIdx.x;
  if (e < n_edges) atomicAdd(&counts[dst[e]], 1);
}

// ---------------- single-pass decoupled-lookback scan ----------------

__global__ __launch_bounds__(256) void scan_kernel(
    const int* __restrict__ counts, int* __restrict__ offsets,
    int* __restrict__ cursor, unsigned int* __restrict__ tstate, int n)
{
  __shared__ int wsum[4];
  __shared__ int s_prefix;
  const int b = blockIdx.x, t = threadIdx.x;
  const int nb = gridDim.x;
  int i0 = b * 1024 + t * 4;
  int c0 = 0, c1 = 0, c2 = 0, c3 = 0;
  if (i0 + 3 < n) {
    int4 c = *(const int4*)&counts[i0];
    c0 = c.x; c1 = c.y; c2 = c.z; c3 = c.w;
  } else {
    if (i0 + 0 < n) c0 = counts[i0 + 0];
    if (i0 + 1 < n) c1 = counts[i0 + 1];
    if (i0 + 2 < n) c2 = counts[i0 + 2];
    if (i0 + 3 < n) c3 = counts[i0 + 3];
  }
  int s = c0 + c1 + c2 + c3;
  int lane = t & 63, wid = t >> 6;
  int inc = s;
  #pragma unroll
  for (int off = 1; off < 64; off <<= 1) {
    int u = __shfl_up(inc, off);
    if (lane >= off) inc += u;
  }
  if (lane == 63) wsum[wid] = inc;
  __syncthreads();
  int wbase = 0;
  for (int w2 = 0; w2 < wid; ++w2) wbase += wsum[w2];
  int total = wsum[0] + wsum[1] + wsum[2] + wsum[3];

  if (t == 0) {
    atomicExch(&tstate[b], 0x40000000u | (unsigned)total);   // PARTIAL
    int prefix = 0;
    int i = b - 1;
    while (i >= 0) {
      unsigned st = atomicAdd(&tstate[i], 0u);
      unsigned fl = st >> 30;
      if (fl == 0u) continue;
      prefix += (int)(st & 0x3FFFFFFFu);
      if (fl == 2u) break;
      --i;
    }
    atomicExch(&tstate[b], 0x80000000u | (unsigned)(prefix + total));  // PREFIX
    s_prefix = prefix;
    if (b == nb - 1) offsets[n] = prefix + total;
  }
  __syncthreads();
  int base = s_prefix + wbase + (inc - s);
  int o0 = base, o1 = o0 + c0, o2 = o1 + c1, o3 = o2 + c2;
  if (i0 + 3 < n) {
    *(int4*)&offsets[i0] = make_int4(o0, o1, o2, o3);
    *(int4*)&cursor[i0]  = make_int4(o0, o1, o2, o3);
  } else {
    if (i0 + 0 < n) { offsets[i0 + 0] = o0; cursor[i0 + 0] = o0; }
    if (i0 + 1 < n) { offsets[i0 + 1] = o1; cursor[i0 + 1] = o1; }
    if (i0 + 2 < n) { offsets[i0 + 2] = o2; cursor[i0 + 2] = o2; }
    if (i0 + 3 < n) { offsets[i0 + 3] = o3; cursor[i0 + 3] = o3; }
  }
}

__global__ void scatter_kernel(const int* __restrict__ src, const int* __restrict__ dst,
                               int* __restrict__ cursor, int* __restrict__ srcp, int n_edges) {
  int e = blockIdx.x * blockDim.x + threadIdx.x;
  if (e < n_edges) {
    int p = atomicAdd(&cursor[dst[e]], 1);
    srcp[p] = src[e];
  }
}

// ---------------- elr1: el/er for layer 1 from x ----------------

__global__ __launch_bounds__(256) void elr_kernel(
    const float* __restrict__ x, const float* __restrict__ wal,
    const float* __restrict__ war, float* __restrict__ el, float* __restrict__ er, int n)
{
  int node = blockIdx.x * 4 + (threadIdx.x >> 6);
  int c = threadIdx.x & 63;
  if (node >= n) return;
  float2 v = *(const float2*)&x[(size_t)node * 128 + c * 2];
  float pl0 = v.x * wal[2 * c] + v.y * wal[2 * c + 1];
  float pl1 = v.x * wal[128 + 2 * c] + v.y * wal[128 + 2 * c + 1];
  float pr0 = v.x * war[2 * c] + v.y * war[2 * c + 1];
  float pr1 = v.x * war[128 + 2 * c] + v.y * war[128 + 2 * c + 1];
  #pragma unroll
  for (int off = 1; off < 64; off <<= 1) {
    pl0 += __shfl_xor(pl0, off);
    pl1 += __shfl_xor(pl1, off);
    pr0 += __shfl_xor(pr0, off);
    pr1 += __shfl_xor(pr1, off);
  }
  if (c == 0) {
    *(float2*)&el[(size_t)node * 2] = make_float2(pl0, pl1);
    *(float2*)&er[(size_t)node * 2] = make_float2(pr0, pr1);
  }
}

// ---------------- alpha: per-edge unnormalized exp scores + per-node den -----
// Wave per node; lanes stride edges. el gathered ONCE per edge (400KB, L2-hot).

__global__ __launch_bounds__(256) void alpha_kernel(
    const float* __restrict__ el, const float* __restrict__ er,
    const int* __restrict__ srcp, const int* __restrict__ offsets,
    float2* __restrict__ xp, float2* __restrict__ denb, int n_nodes)
{
  int node = blockIdx.x * 4 + (threadIdx.x >> 6);
  int lane = threadIdx.x & 63;
  if (node >= n_nodes) return;
  int beg = offsets[node];
  int end = offsets[node + 1];
  float2 ern = *(const float2*)&er[(size_t)node * 2];
  float den0 = 0.f, den1 = 0.f;
  for (int j = beg + lane; j < end; j += 64) {
    int s = srcp[j];
    float2 l = *(const float2*)&el[(size_t)s * 2];
    float e0 = l.x + ern.x;
    float e1 = l.y + ern.y;
    e0 = fminf((e0 >= 0.f) ? e0 : NEG_SLOPE * e0, 60.f);
    e1 = fminf((e1 >= 0.f) ? e1 : NEG_SLOPE * e1, 60.f);
    float x0 = __expf(e0), x1 = __expf(e1);
    xp[j] = make_float2(x0, x1);
    den0 += x0; den1 += x1;
  }
  #pragma unroll
  for (int off = 32; off > 0; off >>= 1) {
    den0 += __shfl_xor(den0, off);
    den1 += __shfl_xor(den1, off);
  }
  if (lane == 0) denb[node] = make_float2(den0, den1);
}

// ---------------- h-space aggregation: pure weighted gather ----------------
// Wave per node; lane c owns cols 2c,2c+1 of both heads. Per edge: broadcast
// srcp/xp + one coalesced 256B bf16 row gather + 4 fma. Output: bf16 hi/lo
// planes (fp32-equivalent for the downstream MFMA GEMM).

#define AGG_E(qj, xj)                                               \
  {                                                                 \
    float f0 = bfbits(qj << 16), f1 = bfbits(qj & 0xFFFF0000u);     \
    a00 = fmaf(xj.x, f0, a00); a01 = fmaf(xj.x, f1, a01);           \
    a10 = fmaf(xj.y, f0, a10); a11 = fmaf(xj.y, f1, a11);           \
  }

__global__ __launch_bounds__(256) void aggregate_kernel(
    const unsigned short* __restrict__ hsrc,   // [N][128] bf16
    const float2* __restrict__ xp, const float2* __restrict__ denb,
    const int* __restrict__ srcp, const int* __restrict__ offsets,
    unsigned int* __restrict__ agghi, unsigned int* __restrict__ agglo,  // [N][128] packed pairs
    int n_nodes)
{
  int node = blockIdx.x * 4 + (threadIdx.x >> 6);
  int c = threadIdx.x & 63;
  if (node >= n_nodes) return;
  int beg = offsets[node];
  int end = offsets[node + 1];

  float a00 = 0.f, a01 = 0.f, a10 = 0.f, a11 = 0.f;
  int j = beg;
  for (; j + 4 <= end; j += 4) {
    int s0 = srcp[j], s1 = srcp[j + 1], s2 = srcp[j + 2], s3 = srcp[j + 3];
    float2 x0 = xp[j], x1 = xp[j + 1], x2 = xp[j + 2], x3 = xp[j + 3];
    unsigned int q0 = *(const unsigned int*)&hsrc[(size_t)s0 * 128 + c * 2];
    unsigned int q1 = *(const unsigned int*)&hsrc[(size_t)s1 * 128 + c * 2];
    unsigned int q2 = *(const unsigned int*)&hsrc[(size_t)s2 * 128 + c * 2];
    unsigned int q3 = *(const unsigned int*)&hsrc[(size_t)s3 * 128 + c * 2];
    AGG_E(q0, x0)
    AGG_E(q1, x1)
    AGG_E(q2, x2)
    AGG_E(q3, x3)
  }
  for (; j < end; ++j) {
    int s0 = srcp[j];
    float2 x0 = xp[j];
    unsigned int q0 = *(const unsigned int*)&hsrc[(size_t)s0 * 128 + c * 2];
    AGG_E(q0, x0)
  }

  float o00 = 0.f, o01 = 0.f, o10 = 0.f, o11 = 0.f;
  if (end > beg) {
    float2 dn = denb[node];
    float i0 = 1.0f / dn.x, i1 = 1.0f / dn.y;
    o00 = a00 * i0; o01 = a01 * i0;
    o10 = a10 * i1; o11 = a11 * i1;
  }
  unsigned int lo0, lo1;
  unsigned int hi0 = pack_hilo(o00, o01, &lo0);
  unsigned int hi1 = pack_hilo(o10, o11, &lo1);
  agghi[(size_t)node * 128 + c]      = hi0;
  agglo[(size_t)node * 128 + c]      = lo0;
  agghi[(size_t)node * 128 + 64 + c] = hi1;
  agglo[(size_t)node * 128 + 64 + c] = lo1;
}

// ---------------- gemm1: hbuf = 0.5*(agg0@W0h0 + agg1@W0h1) + bmean; el2/er2 --
// A-frags load directly from agghi/agglo bf16 planes (no in-register split).

__global__ __launch_bounds__(256) void gemm1_kernel(
    const unsigned short* __restrict__ agghi, const unsigned short* __restrict__ agglo, // [N][256] bf16
    const unsigned short* __restrict__ Whi, const unsigned short* __restrict__ Wlo,     // layer-0 base
    const float* __restrict__ wal2, const float* __restrict__ war2,
    const float* __restrict__ b0,
    unsigned short* __restrict__ hb16, float* __restrict__ el, float* __restrict__ er,
    int n_nodes)
{
  __shared__ unsigned short lds_bh[16384];
  __shared__ unsigned short lds_bl[16384];
  const int tid = threadIdx.x;
  const int w = tid >> 6;
  const int lane = tid & 63;
  const int lrow = lane & 15;
  const int g = lane >> 4;
  const int node0 = blockIdx.x * 64 + w * 16;

  int arow = node0 + lrow;
  int arow_c = (arow < n_nodes) ? arow : (n_nodes - 1);

  f32x4_t acc[8];
  #pragma unroll
  for (int i = 0; i < 8; ++i) acc[i] = (f32x4_t){0.f, 0.f, 0.f, 0.f};

  for (int hb = 0; hb < 2; ++hb) {
    __syncthreads();
    {
      const uint4* gh = (const uint4*)(Whi + (size_t)hb * 16384);
      const uint4* gl = (const uint4*)(Wlo + (size_t)hb * 16384);
      uint4* lh = (uint4*)lds_bh;
      uint4* ll = (uint4*)lds_bl;
      #pragma unroll
      for (int r = 0; r < 8; ++r) {
        lh[tid + 256 * r] = gh[tid + 256 * r];
        ll[tid + 256 * r] = gl[tid + 256 * r];
      }
    }
    __syncthreads();
    const unsigned short* ah_p = agghi + (size_t)arow_c * 256 + hb * 128 + g * 8;
    const unsigned short* al_p = agglo + (size_t)arow_c * 256 + hb * 128 + g * 8;
    #pragma unroll
    for (int s = 0; s < 4; ++s) {
      bf16x8_t ahi = *(const bf16x8_t*)(ah_p + s * 32);
      bf16x8_t alo = *(const bf16x8_t*)(al_p + s * 32);
      #pragma unroll
      for (int ct = 0; ct < 8; ++ct) {
        bf16x8_t bh = *(const bf16x8_t*)&lds_bh[((s * 8 + ct) * 64 + lane) * 8];
        bf16x8_t bl = *(const bf16x8_t*)&lds_bl[((s * 8 + ct) * 64 + lane) * 8];
        acc[ct] = __builtin_amdgcn_mfma_f32_16x16x32_bf16(ahi, bh, acc[ct], 0, 0, 0);
        acc[ct] = __builtin_amdgcn_mfma_f32_16x16x32_bf16(alo, bh, acc[ct], 0, 0, 0);
        acc[ct] = __builtin_amdgcn_mfma_f32_16x16x32_bf16(ahi, bl, acc[ct], 0, 0, 0);
      }
    }
  }

  float bm[8], alc0[8], alc1[8], arc0[8], arc1[8];
  #pragma unroll
  for (int ct = 0; ct < 8; ++ct) {
    int col = ct * 16 + lrow;
    bm[ct] = 0.5f * (b0[col] + b0[128 + col]);
    alc0[ct] = wal2[col];
    alc1[ct] = wal2[128 + col];
    arc0[ct] = war2[col];
    arc1[ct] = war2[128 + col];
  }
  #pragma unroll
  for (int r = 0; r < 4; ++r) {
    int orow = node0 + g * 4 + r;
    bool ok = orow < n_nodes;
    float pl0 = 0.f, pl1 = 0.f, pr0 = 0.f, pr1 = 0.f;
    #pragma unroll
    for (int ct = 0; ct < 8; ++ct) {
      float v = fmaf(acc[ct][r], 0.5f, bm[ct]);
      pl0 += v * alc0[ct];
      pl1 += v * alc1[ct];
      pr0 += v * arc0[ct];
      pr1 += v * arc1[ct];
      if (ok) hb16[(size_t)orow * 128 + ct * 16 + lrow] = f2bf(v);
    }
    #pragma unroll
    for (int off = 1; off < 16; off <<= 1) {
      pl0 += __shfl_xor(pl0, off);
      pl1 += __shfl_xor(pl1, off);
      pr0 += __shfl_xor(pr0, off);
      pr1 += __shfl_xor(pr1, off);
    }
    if (lrow == 0 && ok) {
      *(float2*)&el[(size_t)orow * 2] = make_float2(pl0, pl1);
      *(float2*)&er[(size_t)orow * 2] = make_float2(pr0, pr1);
    }
  }
}

// ---------------- gemm2: out[:, hb*128:+128] = agg[:,hb,:] @ W1_hb + b1_hb ----

__global__ __launch_bounds__(256) void gemm2_kernel(
    const unsigned short* __restrict__ agghi, const unsigned short* __restrict__ agglo,
    const unsigned short* __restrict__ Whi, const unsigned short* __restrict__ Wlo, // layer-1 base
    const float* __restrict__ b1, float* __restrict__ out, int n_nodes)
{
  __shared__ unsigned short lds_bh[16384];
  __shared__ unsigned short lds_bl[16384];
  const int tid = threadIdx.x;
  const int w = tid >> 6;
  const int lane = tid & 63;
  const int lrow = lane & 15;
  const int g = lane >> 4;
  const int hb = blockIdx.y;
  const int node0 = blockIdx.x * 64 + w * 16;

  {
    const uint4* gh = (const uint4*)(Whi + (size_t)hb * 16384);
    const uint4* gl = (const uint4*)(Wlo + (size_t)hb * 16384);
    uint4* lh = (uint4*)lds_bh;
    uint4* ll = (uint4*)lds_bl;
    #pragma unroll
    for (int r = 0; r < 8; ++r) {
      lh[tid + 256 * r] = gh[tid + 256 * r];
      ll[tid + 256 * r] = gl[tid + 256 * r];
    }
  }

  int arow = node0 + lrow;
  int arow_c = (arow < n_nodes) ? arow : (n_nodes - 1);
  const unsigned short* ah_p = agghi + (size_t)arow_c * 256 + hb * 128 + g * 8;
  const unsigned short* al_p = agglo + (size_t)arow_c * 256 + hb * 128 + g * 8;

  f32x4_t acc[8];
  #pragma unroll
  for (int i = 0; i < 8; ++i) acc[i] = (f32x4_t){0.f, 0.f, 0.f, 0.f};

  __syncthreads();

  #pragma unroll
  for (int s = 0; s < 4; ++s) {
    bf16x8_t ahi = *(const bf16x8_t*)(ah_p + s * 32);
    bf16x8_t alo = *(const bf16x8_t*)(al_p + s * 32);
    #pragma unroll
    for (int ct = 0; ct < 8; ++ct) {
      bf16x8_t bh = *(const bf16x8_t*)&lds_bh[((s * 8 + ct) * 64 + lane) * 8];
      bf16x8_t bl = *(const bf16x8_t*)&lds_bl[((s * 8 + ct) * 64 + lane) * 8];
      acc[ct] = __builtin_amdgcn_mfma_f32_16x16x32_bf16(ahi, bh, acc[ct], 0, 0, 0);
      acc[ct] = __builtin_amdgcn_mfma_f32_16x16x32_bf16(alo, bh, acc[ct], 0, 0, 0);
      acc[ct] = __builtin_amdgcn_mfma_f32_16x16x32_bf16(ahi, bl, acc[ct], 0, 0, 0);
    }
  }

  float bc[8];
  #pragma unroll
  for (int ct = 0; ct < 8; ++ct) bc[ct] = b1[hb * 128 + ct * 16 + lrow];
  #pragma unroll
  for (int r = 0; r < 4; ++r) {
    int orow = node0 + g * 4 + r;
    if (orow >= n_nodes) continue;
    #pragma unroll
    for (int ct = 0; ct < 8; ++ct) {
      out[(size_t)orow * 256 + hb * 128 + ct * 16 + lrow] = acc[ct][r] + bc[ct];
    }
  }
}

// ---------------- launch ----------------

extern "C" void kernel_launch(void* const* d_in, const int* in_sizes, int n_in,
                              void* d_out, int out_size, void* d_ws, size_t ws_size,
                              hipStream_t stream) {
  const float* x   = (const float*)d_in[0];
  const float* Ws  = (const float*)d_in[1];
  const float* als = (const float*)d_in[2];
  const float* ars = (const float*)d_in[3];
  const float* bs  = (const float*)d_in[4];
  const int*   src = (const int*)d_in[5];
  const int*   dst = (const int*)d_in[6];
  const int N = in_sizes[0] / 128;   // 50000
  const int E = in_sizes[5];         // 800000
  float* out = (float*)d_out;

  char* ws = (char*)d_ws;
  auto alloc = [&](size_t bytes) {
    char* p = ws;
    ws += (bytes + 255) & ~(size_t)255;
    return p;
  };
  unsigned int* agghi = (unsigned int*)alloc((size_t)N * 128 * 4);   // bf16 [N][256] hi
  unsigned int* agglo = (unsigned int*)alloc((size_t)N * 128 * 4);   // bf16 [N][256] lo
  unsigned short* xb16 = (unsigned short*)alloc((size_t)N * 128 * 2);
  unsigned short* hb16 = (unsigned short*)alloc((size_t)N * 128 * 2);
  float2* xp     = (float2*)alloc((size_t)E * 8);
  float2* denb   = (float2*)alloc((size_t)N * 8);
  int*   srcp    = (int*)alloc((size_t)E * 4);
  int*   offsets = (int*)alloc((size_t)(N + 1) * 4);
  int*   cursor  = (int*)alloc((size_t)N * 4);
  int*   counts  = (int*)alloc((size_t)N * 4);
  float* el      = (float*)alloc((size_t)N * 2 * 4);
  float* er      = (float*)alloc((size_t)N * 2 * 4);
  float* wal     = (float*)alloc((size_t)512 * 4);
  float* war     = (float*)alloc((size_t)512 * 4);
  unsigned int* tstate = (unsigned int*)alloc((size_t)64 * 4);
  unsigned short* Whi = (unsigned short*)alloc((size_t)65536 * 2);
  unsigned short* Wlo = (unsigned short*)alloc((size_t)65536 * 2);

  const int nb = (N + 1023) / 1024;
  const int nxb = (N * 128 + 1023) / 1024;
  const int init_blocks = 36 + nxb + (N + 255) / 256;
  const int ngrp = (N + 3) / 4;
  const int ntiles = (N + 63) / 64;

  init_kernel<<<dim3(init_blocks), dim3(256), 0, stream>>>(
      Ws, als, ars, x, Whi, Wlo, wal, war, xb16, counts, tstate, N);
  hist_kernel<<<dim3((E + 255) / 256), dim3(256), 0, stream>>>(dst, counts, E);
  scan_kernel<<<dim3(nb), dim3(256), 0, stream>>>(counts, offsets, cursor, tstate, N);
  scatter_kernel<<<dim3((E + 255) / 256), dim3(256), 0, stream>>>(src, dst, cursor, srcp, E);

  // layer 1
  elr_kernel<<<dim3(ngrp), dim3(256), 0, stream>>>(x, wal, war, el, er, N);
  alpha_kernel<<<dim3(ngrp), dim3(256), 0, stream>>>(el, er, srcp, offsets, xp, denb, N);
  aggregate_kernel<<<dim3(ngrp), dim3(256), 0, stream>>>(
      xb16, xp, denb, srcp, offsets, agghi, agglo, N);
  gemm1_kernel<<<dim3(ntiles), dim3(256), 0, stream>>>(
      (const unsigned short*)agghi, (const unsigned short*)agglo,
      Whi, Wlo, wal + 256, war + 256, bs, hb16, el, er, N);
  // layer 2
  alpha_kernel<<<dim3(ngrp), dim3(256), 0, stream>>>(el, er, srcp, offsets, xp, denb, N);
  aggregate_kernel<<<dim3(ngrp), dim3(256), 0, stream>>>(
      hb16, xp, denb, srcp, offsets, agghi, agglo, N);
  gemm2_kernel<<<dim3(ntiles, 2), dim3(256), 0, stream>>>(
      (const unsigned short*)agghi, (const unsigned short*)agglo,
      Whi + 32768, Wlo + 32768, bs + 256, out, N);
}